// Round 12
// baseline (265.168 us; speedup 1.0000x reference)
//
#include <hip/hip_runtime.h>
#include <stdint.h>

#define BATCH 8
#define NNODE 1024
#define INF 768
#define OUTF 512
#define MTOT (BATCH * NNODE) /* 8192 */
#define NBLK 512

typedef __attribute__((ext_vector_type(8))) short short8;
typedef __attribute__((ext_vector_type(4))) short short4v;
typedef __attribute__((ext_vector_type(4))) float floatx4;

__device__ __forceinline__ unsigned short f2bf(float f) {
  union { float f; unsigned u; } v; v.f = f;
  unsigned r = v.u + 0x7fffu + ((v.u >> 16) & 1u);
  return (unsigned short)(r >> 16);
}

__device__ __forceinline__ void gload_lds16(const void* g, void* l) {
  __builtin_amdgcn_global_load_lds(
      (const __attribute__((address_space(1))) void*)g,
      (__attribute__((address_space(3))) void*)l, 16, 0, 0);
}

// software grid barrier: counters zeroed by hipMemsetAsync each launch
__device__ __forceinline__ void gridbar(int* bar, int idx) {
  __syncthreads();
  if (threadIdx.x == 0) {
    __threadfence();
    atomicAdd(&bar[idx], 1);
    while (__hip_atomic_load(&bar[idx], __ATOMIC_ACQUIRE,
                             __HIP_MEMORY_SCOPE_AGENT) < NBLK) {
      __builtin_amdgcn_s_sleep(2);
    }
    __threadfence();
  }
  __syncthreads();
}

__global__ __launch_bounds__(512, 4) void mega_kernel(
    const float* __restrict__ h, const int* __restrict__ adj,
    const int* __restrict__ positions, const float* __restrict__ W,
    const float* __restrict__ a, const float* __restrict__ pos_table,
    float* __restrict__ hp, float* __restrict__ att,
    short* __restrict__ Wt, short* __restrict__ Wht,
    float* __restrict__ f12, short* __restrict__ hbfattbf,
    int* __restrict__ bar) {
  __shared__ short smem[24576];   // 48KB; aliased per phase
  int blk = blockIdx.x;
  int t = threadIdx.x;

  // ================= P0: prep =================
  {
    short* hbf = hbfattbf;
    size_t tid = (size_t)blk * 512 + t;
#pragma unroll
    for (int i = 0; i < 3; ++i) {           // h -> bf16 (3 chunks/thread)
      size_t idx = (tid + (size_t)i * 262144) * 8;
      float4 v0 = *(const float4*)&h[idx];
      float4 v1 = *(const float4*)&h[idx + 4];
      short8 o;
      o[0] = (short)f2bf(v0.x); o[1] = (short)f2bf(v0.y);
      o[2] = (short)f2bf(v0.z); o[3] = (short)f2bf(v0.w);
      o[4] = (short)f2bf(v1.x); o[5] = (short)f2bf(v1.y);
      o[6] = (short)f2bf(v1.z); o[7] = (short)f2bf(v1.w);
      *(short8*)&hbf[idx] = o;
    }
    if (blk < 384) {                        // W -> Wt 32x32 tile transpose
      float* tile = (float*)smem;           // [32][33]
      int o0 = (blk & 15) * 32, k0 = (blk >> 4) * 32;
      int x = t & 31, y = t >> 5;           // y in [0,16)
#pragma unroll
      for (int q = 0; q < 2; ++q) {
        int r = y * 2 + q;
        tile[r * 33 + x] = W[(size_t)(k0 + r) * OUTF + o0 + x];
      }
      __syncthreads();
#pragma unroll
      for (int q = 0; q < 2; ++q) {
        int r = y * 2 + q;
        Wt[(size_t)(o0 + r) * INF + k0 + x] = (short)f2bf(tile[x * 33 + r]);
      }
    } else if (blk < 392) {                 // zero f12 (2*MTOT floats)
      int z = blk - 384;
      float4 zz = make_float4(0.f, 0.f, 0.f, 0.f);
      *(float4*)&f12[z * 2048 + t * 4] = zz;
    }
  }
  gridbar(bar, 0);

  // ================= P1: gemm1 (R9 body) =================
  {
    const short* hbf = hbfattbf;
    int bid = (blk & 7) * 64 + (blk >> 3);   // XCD swizzle (512 % 8 == 0)
    int nt = bid & 3, mt = bid >> 2;
    int M0 = mt * 64, N0 = nt * 128;
    int wv = t >> 6, lane = t & 63;
    int wr = (wv >> 2) * 32, wc = (wv & 3) * 32;
    int l16 = lane & 15, kq = lane >> 4;

    floatx4 acc[2][2] = {};

    auto stage = [&](int buf, int kt) {
      {  // A: 64x64 bf16, 512 chunks, 1/thread
        int row = t >> 3;
        int cg = (t & 7) ^ (row & 7);
        gload_lds16(&hbf[(size_t)(M0 + row) * INF + kt * 64 + cg * 8],
                    &smem[buf * 4096 + t * 8]);
      }
#pragma unroll
      for (int i = 0; i < 2; ++i) {  // B: 128x64 bf16, 1024 chunks, 2/thread
        int q = t + i * 512;
        int row = q >> 3;
        int cg = (q & 7) ^ (row & 7);
        gload_lds16(&Wt[(size_t)(N0 + row) * INF + kt * 64 + cg * 8],
                    &smem[8192 + buf * 8192 + q * 8]);
      }
    };

    stage(0, 0);
    __syncthreads();
    for (int kt = 0; kt < 12; ++kt) {
      if (kt < 11) stage((kt + 1) & 1, kt + 1);
      const short* As = &smem[(kt & 1) * 4096];
      const short* Bs = &smem[8192 + (kt & 1) * 8192];
#pragma unroll
      for (int ks = 0; ks < 2; ++ks) {
        short8 af[2], bfv[2];
#pragma unroll
        for (int mi = 0; mi < 2; ++mi) {
          int r = wr + mi * 16 + l16;
          af[mi] = *(const short8*)&As[r * 64 + (((ks * 4 + kq) ^ (r & 7)) * 8)];
        }
#pragma unroll
        for (int ni = 0; ni < 2; ++ni) {
          int r = wc + ni * 16 + l16;
          bfv[ni] = *(const short8*)&Bs[r * 64 + (((ks * 4 + kq) ^ (r & 7)) * 8)];
        }
#pragma unroll
        for (int mi = 0; mi < 2; ++mi)
#pragma unroll
          for (int ni = 0; ni < 2; ++ni)
            acc[mi][ni] = __builtin_amdgcn_mfma_f32_16x16x32_bf16(af[mi], bfv[ni], acc[mi][ni], 0, 0, 0);
      }
      __syncthreads();
    }

    int oc0 = N0 + wc + l16;
    int oc1 = oc0 + 16;
#pragma unroll
    for (int mi = 0; mi < 2; ++mi)
#pragma unroll
      for (int j = 0; j < 4; ++j) {
        int row = M0 + wr + mi * 16 + kq * 4 + j;
        int pos = positions[row];
        acc[mi][0][j] += pos_table[(size_t)pos * OUTF + oc0];
        acc[mi][1][j] += pos_table[(size_t)pos * OUTF + oc1];
      }
    short* T = smem;   // T[128 N-rows][64 M-cols], stride 72
#pragma unroll
    for (int mi = 0; mi < 2; ++mi)
#pragma unroll
      for (int ni = 0; ni < 2; ++ni)
#pragma unroll
        for (int j = 0; j < 4; ++j)
          T[(wc + ni * 16 + l16) * 72 + wr + mi * 16 + kq * 4 + j] =
              (short)f2bf(acc[mi][ni][j]);
    float a10 = a[oc0], a11 = a[oc1];
    float a20 = a[OUTF + oc0], a21 = a[OUTF + oc1];
    float v1[8], v2[8];
#pragma unroll
    for (int mi = 0; mi < 2; ++mi)
#pragma unroll
      for (int j = 0; j < 4; ++j) {
        v1[mi * 4 + j] = acc[mi][0][j] * a10 + acc[mi][1][j] * a11;
        v2[mi * 4 + j] = acc[mi][0][j] * a20 + acc[mi][1][j] * a21;
      }
#pragma unroll
    for (int mlen = 4; mlen >= 1; mlen >>= 1) {
      bool hi = (l16 & mlen) != 0;
#pragma unroll
      for (int i = 0; i < mlen; ++i) {
        float k1 = hi ? v1[mlen + i] : v1[i];
        float s1 = hi ? v1[i] : v1[mlen + i];
        float k2 = hi ? v2[mlen + i] : v2[i];
        float s2 = hi ? v2[i] : v2[mlen + i];
        v1[i] = k1 + __shfl_xor(s1, mlen);
        v2[i] = k2 + __shfl_xor(s2, mlen);
      }
    }
    v1[0] += __shfl_xor(v1[0], 8);
    v2[0] += __shfl_xor(v2[0], 8);
    if (l16 < 8) {
      int rrow = M0 + wr + ((l16 >> 2) & 1) * 16 + kq * 4 + (l16 & 3);
      atomicAdd(&f12[rrow], v1[0]);
      atomicAdd(&f12[MTOT + rrow], v2[0]);
    }
    __syncthreads();
    int bb = M0 >> 10, i0 = M0 & 1023;
#pragma unroll
    for (int i = 0; i < 2; ++i) {
      int c = t + i * 512;
      int row = c >> 3;
      int mc = (c & 7) * 8;
      short8 vv = *(const short8*)&T[row * 72 + mc];
      *(short8*)&Wht[((size_t)bb * OUTF + N0 + row) * NNODE + i0 + mc] = vv;
    }
  }
  gridbar(bar, 1);

  // ================= P2: softmax (1 wave per row, 2 rows/wave) =================
  {
    short* attbf = hbfattbf;
    int wv = t >> 6, lane = t & 63;
#pragma unroll
    for (int rr = 0; rr < 2; ++rr) {
      int m = blk * 16 + wv * 2 + rr;
      int b = m >> 10;
      float f1v = f12[m];
      const float* f2b = f12 + MTOT + b * NNODE;
      const int* adjrow = adj + (size_t)m * NNODE;
      float e[16];
#pragma unroll
      for (int i = 0; i < 4; ++i) {
        int col = lane * 4 + i * 256;
        int4 av = *(const int4*)&adjrow[col];
        float4 fv = *(const float4*)&f2b[col];
        float x;
        x = f1v + fv.x; x = x >= 0.f ? x : 0.2f * x; e[i * 4 + 0] = av.x > 0 ? x : -9e15f;
        x = f1v + fv.y; x = x >= 0.f ? x : 0.2f * x; e[i * 4 + 1] = av.y > 0 ? x : -9e15f;
        x = f1v + fv.z; x = x >= 0.f ? x : 0.2f * x; e[i * 4 + 2] = av.z > 0 ? x : -9e15f;
        x = f1v + fv.w; x = x >= 0.f ? x : 0.2f * x; e[i * 4 + 3] = av.w > 0 ? x : -9e15f;
      }
      float mx = e[0];
#pragma unroll
      for (int i = 1; i < 16; ++i) mx = fmaxf(mx, e[i]);
#pragma unroll
      for (int off = 1; off < 64; off <<= 1) mx = fmaxf(mx, __shfl_xor(mx, off));
      float s = 0.f;
#pragma unroll
      for (int i = 0; i < 16; ++i) { e[i] = expf(e[i] - mx); s += e[i]; }
#pragma unroll
      for (int off = 1; off < 64; off <<= 1) s += __shfl_xor(s, off);
      float inv = 1.f / s;
      float* attrow = att + (size_t)m * NNODE;
      short* abrow = attbf + (size_t)m * NNODE;
#pragma unroll
      for (int i = 0; i < 4; ++i) {
        int col = lane * 4 + i * 256;
        float4 o = make_float4(e[i * 4] * inv, e[i * 4 + 1] * inv,
                               e[i * 4 + 2] * inv, e[i * 4 + 3] * inv);
        *(float4*)&attrow[col] = o;
        short4v ob;
        ob[0] = (short)f2bf(o.x); ob[1] = (short)f2bf(o.y);
        ob[2] = (short)f2bf(o.z); ob[3] = (short)f2bf(o.w);
        *(short4v*)&abrow[col] = ob;
      }
    }
  }
  gridbar(bar, 2);

  // ================= P3: pv (R9 body) =================
  {
    const short* attbf = hbfattbf;
    int bid = (blk & 7) * 64 + (blk >> 3);   // XCD swizzle: one batch per XCD
    int nt = bid & 3, mt = bid >> 2;
    int M0 = mt * 64, N0 = nt * 128;
    const short* Wb = Wht + (size_t)(M0 >> 10) * OUTF * NNODE;
    int wv = t >> 6, lane = t & 63;
    int wr = (wv >> 2) * 32, wc = (wv & 3) * 32;
    int l16 = lane & 15, kq = lane >> 4;

    floatx4 acc[2][2] = {};

    auto stage = [&](int buf, int kt) {
      {
        int row = t >> 3;
        int cg = (t & 7) ^ (row & 7);
        gload_lds16(&attbf[(size_t)(M0 + row) * NNODE + kt * 64 + cg * 8],
                    &smem[buf * 4096 + t * 8]);
      }
#pragma unroll
      for (int i = 0; i < 2; ++i) {
        int q = t + i * 512;
        int row = q >> 3;
        int cg = (q & 7) ^ (row & 7);
        gload_lds16(&Wb[(size_t)(N0 + row) * NNODE + kt * 64 + cg * 8],
                    &smem[8192 + buf * 8192 + q * 8]);
      }
    };

    stage(0, 0);
    __syncthreads();
    for (int kt = 0; kt < 16; ++kt) {
      if (kt < 15) stage((kt + 1) & 1, kt + 1);
      const short* As = &smem[(kt & 1) * 4096];
      const short* Bs = &smem[8192 + (kt & 1) * 8192];
#pragma unroll
      for (int ks = 0; ks < 2; ++ks) {
        short8 af[2], bfv[2];
#pragma unroll
        for (int mi = 0; mi < 2; ++mi) {
          int r = wr + mi * 16 + l16;
          af[mi] = *(const short8*)&As[r * 64 + (((ks * 4 + kq) ^ (r & 7)) * 8)];
        }
#pragma unroll
        for (int ni = 0; ni < 2; ++ni) {
          int r = wc + ni * 16 + l16;
          bfv[ni] = *(const short8*)&Bs[r * 64 + (((ks * 4 + kq) ^ (r & 7)) * 8)];
        }
#pragma unroll
        for (int mi = 0; mi < 2; ++mi)
#pragma unroll
          for (int ni = 0; ni < 2; ++ni)
            acc[mi][ni] = __builtin_amdgcn_mfma_f32_16x16x32_bf16(af[mi], bfv[ni], acc[mi][ni], 0, 0, 0);
      }
      __syncthreads();
    }

#pragma unroll
    for (int mi = 0; mi < 2; ++mi)
#pragma unroll
      for (int j = 0; j < 4; ++j) {
        int row = M0 + wr + mi * 16 + kq * 4 + j;
#pragma unroll
        for (int ni = 0; ni < 2; ++ni) {
          int col = N0 + wc + ni * 16 + l16;
          hp[(size_t)row * OUTF + col] = acc[mi][ni][j];
        }
      }
  }
}

extern "C" void kernel_launch(void* const* d_in, const int* in_sizes, int n_in,
                              void* d_out, int out_size, void* d_ws, size_t ws_size,
                              hipStream_t stream) {
  const float* h = (const float*)d_in[0];
  const int* adj = (const int*)d_in[1];
  const int* positions = (const int*)d_in[2];
  const float* W = (const float*)d_in[3];
  const float* a = (const float*)d_in[4];
  const float* pos_table = (const float*)d_in[5];

  float* hp = (float*)d_out;                       // 8192*512
  float* att = hp + (size_t)MTOT * OUTF;           // 8192*1024

  char* ws = (char*)d_ws;
  short* Wt = (short*)ws;                                   // 786432 B
  short* Wht = (short*)(ws + 786432);                       // 8388608 B
  float* f12 = (float*)(ws + 786432 + 8388608);             // 65536 B
  int* bar = (int*)(ws + 786432 + 8388608 + 65536);         // 256 B
  short* hbfattbf = (short*)(ws + 786432 + 8388608 + 65536 + 256);  // 16.8 MB

  hipMemsetAsync(bar, 0, 3 * sizeof(int), stream);
  mega_kernel<<<512, 512, 0, stream>>>(h, adj, positions, W, a, pos_table,
                                       hp, att, Wt, Wht, f12, hbfattbf, bar);
}

// Round 13
// 54.939 us; speedup vs baseline: 4.8266x; 4.8266x over previous
//
#include <hip/hip_runtime.h>
#include <stdint.h>

#define BATCH 8
#define NNODE 1024
#define INF 768
#define OUTF 512
#define MTOT (BATCH * NNODE) /* 8192 */

typedef __attribute__((ext_vector_type(8))) short short8;
typedef __attribute__((ext_vector_type(4))) short short4v;
typedef __attribute__((ext_vector_type(4))) float floatx4;

__device__ __forceinline__ unsigned short f2bf(float f) {
  union { float f; unsigned u; } v; v.f = f;
  unsigned r = v.u + 0x7fffu + ((v.u >> 16) & 1u);
  return (unsigned short)(r >> 16);
}

__device__ __forceinline__ void gload_lds16(const void* g, void* l) {
  __builtin_amdgcn_global_load_lds(
      (const __attribute__((address_space(1))) void*)g,
      (__attribute__((address_space(3))) void*)l, 16, 0, 0);
}

// ------------- prep: h->bf16 (+zero f12), W -> Wt (512x768 bf16) -------------
__global__ __launch_bounds__(256) void prep_kernel(
    const float* __restrict__ h, const float* __restrict__ W,
    short* __restrict__ hbf, short* __restrict__ Wt, float* __restrict__ f12) {
  __shared__ float tile[32][33];
  int bid = blockIdx.x;
  int t = threadIdx.x;
  if (bid < 3072) {
    size_t i = ((size_t)bid * 256 + t) * 8;
    float4 v0 = *(const float4*)&h[i];
    float4 v1 = *(const float4*)&h[i + 4];
    short8 o;
    o[0] = (short)f2bf(v0.x); o[1] = (short)f2bf(v0.y);
    o[2] = (short)f2bf(v0.z); o[3] = (short)f2bf(v0.w);
    o[4] = (short)f2bf(v1.x); o[5] = (short)f2bf(v1.y);
    o[6] = (short)f2bf(v1.z); o[7] = (short)f2bf(v1.w);
    *(short8*)&hbf[i] = o;
    if (bid < 16) {
      float4 z = make_float4(0.f, 0.f, 0.f, 0.f);
      *(float4*)&f12[bid * 1024 + t * 4] = z;
    }
  } else {
    int tb = bid - 3072;             // 384 tiles: 16 (o) x 24 (k)
    int o0 = (tb & 15) * 32;
    int k0 = (tb >> 4) * 32;
    int x = t & 31, y = t >> 5;
#pragma unroll
    for (int q = 0; q < 4; ++q) {
      int r = y * 4 + q;
      tile[r][x] = W[(size_t)(k0 + r) * OUTF + o0 + x];
    }
    __syncthreads();
#pragma unroll
    for (int q = 0; q < 4; ++q) {
      int r = y * 4 + q;
      Wt[(size_t)(o0 + r) * INF + k0 + x] = (short)f2bf(tile[x][r]);
    }
  }
}

// ---- GEMM1 fused: Wh = h@W + pos -> Wht (bf16 transposed) + f1/f2 ----
// BM=64 BN=128 BK=64, grid 512 (2 blocks/CU), 8 waves (2Mx4N), wave 32x32.
__global__ __launch_bounds__(512) void gemm1_kernel(
    const short* __restrict__ hbf, const short* __restrict__ Wt,
    const int* __restrict__ positions, const float* __restrict__ pos_table,
    const float* __restrict__ a, float* __restrict__ f12,
    short* __restrict__ Wht) {
  __shared__ short smem[24576];   // 48KB: As[2]@4096 | Bs[2]@8192 ; T reuses
  int bid0 = blockIdx.x;
  int bid = (bid0 & 7) * 64 + (bid0 >> 3);   // XCD swizzle (512 % 8 == 0)
  int nt = bid & 3, mt = bid >> 2;           // 4 N-tiles x 128 M-tiles
  int M0 = mt * 64, N0 = nt * 128;
  int t = threadIdx.x;
  int wv = t >> 6, lane = t & 63;
  int wr = (wv >> 2) * 32, wc = (wv & 3) * 32;
  int l16 = lane & 15, kq = lane >> 4;

  floatx4 acc[2][2] = {};

  auto stage = [&](int buf, int kt) {
    {  // A: 64x64 tile, 512 chunks, 1/thread
      int row = t >> 3;
      int cg = (t & 7) ^ (row & 7);
      gload_lds16(&hbf[(size_t)(M0 + row) * INF + kt * 64 + cg * 8],
                  &smem[buf * 4096 + (t >> 6) * 512 + (t & 63) * 8]);
    }
#pragma unroll
    for (int i = 0; i < 2; ++i) {  // B: 128x64 tile, 1024 chunks, 2/thread
      int q = wv * 64 + lane + i * 512;
      int row = q >> 3;
      int cg = (q & 7) ^ (row & 7);
      gload_lds16(&Wt[(size_t)(N0 + row) * INF + kt * 64 + cg * 8],
                  &smem[8192 + buf * 8192 + (wv * 64 + i * 512) * 8]);
    }
  };

  stage(0, 0);
  __syncthreads();
  for (int kt = 0; kt < 12; ++kt) {
    if (kt < 11) stage((kt + 1) & 1, kt + 1);
    const short* As = &smem[(kt & 1) * 4096];
    const short* Bs = &smem[8192 + (kt & 1) * 8192];
#pragma unroll
    for (int ks = 0; ks < 2; ++ks) {
      short8 af[2], bfv[2];
#pragma unroll
      for (int mi = 0; mi < 2; ++mi) {
        int r = wr + mi * 16 + l16;
        af[mi] = *(const short8*)&As[r * 64 + (((ks * 4 + kq) ^ (r & 7)) * 8)];
      }
#pragma unroll
      for (int ni = 0; ni < 2; ++ni) {
        int r = wc + ni * 16 + l16;
        bfv[ni] = *(const short8*)&Bs[r * 64 + (((ks * 4 + kq) ^ (r & 7)) * 8)];
      }
#pragma unroll
      for (int mi = 0; mi < 2; ++mi)
#pragma unroll
        for (int ni = 0; ni < 2; ++ni)
          acc[mi][ni] = __builtin_amdgcn_mfma_f32_16x16x32_bf16(af[mi], bfv[ni], acc[mi][ni], 0, 0, 0);
    }
    __syncthreads();
  }

  // ---- epilogue ----
  int oc0 = N0 + wc + l16;
  int oc1 = oc0 + 16;
#pragma unroll
  for (int mi = 0; mi < 2; ++mi)
#pragma unroll
    for (int j = 0; j < 4; ++j) {
      int row = M0 + wr + mi * 16 + kq * 4 + j;
      int pos = positions[row];
      acc[mi][0][j] += pos_table[(size_t)pos * OUTF + oc0];
      acc[mi][1][j] += pos_table[(size_t)pos * OUTF + oc1];
    }
  // transposed bf16 tile: T[128 N-rows][64 M-cols], stride 72 (2-way alias, free)
  short* T = smem;
#pragma unroll
  for (int mi = 0; mi < 2; ++mi)
#pragma unroll
    for (int ni = 0; ni < 2; ++ni)
#pragma unroll
      for (int j = 0; j < 4; ++j)
        T[(wc + ni * 16 + l16) * 72 + wr + mi * 16 + kq * 4 + j] =
            (short)f2bf(acc[mi][ni][j]);
  // f1/f2 partials: 8-entry butterfly over 16 lanes + final xor-8
  float a10 = a[oc0], a11 = a[oc1];
  float a20 = a[OUTF + oc0], a21 = a[OUTF + oc1];
  float v1[8], v2[8];
#pragma unroll
  for (int mi = 0; mi < 2; ++mi)
#pragma unroll
    for (int j = 0; j < 4; ++j) {
      v1[mi * 4 + j] = acc[mi][0][j] * a10 + acc[mi][1][j] * a11;
      v2[mi * 4 + j] = acc[mi][0][j] * a20 + acc[mi][1][j] * a21;
    }
#pragma unroll
  for (int mlen = 4; mlen >= 1; mlen >>= 1) {
    bool hi = (l16 & mlen) != 0;
#pragma unroll
    for (int i = 0; i < mlen; ++i) {
      float k1 = hi ? v1[mlen + i] : v1[i];
      float s1 = hi ? v1[i] : v1[mlen + i];
      float k2 = hi ? v2[mlen + i] : v2[i];
      float s2 = hi ? v2[i] : v2[mlen + i];
      v1[i] = k1 + __shfl_xor(s1, mlen);
      v2[i] = k2 + __shfl_xor(s2, mlen);
    }
  }
  v1[0] += __shfl_xor(v1[0], 8);
  v2[0] += __shfl_xor(v2[0], 8);
  if (l16 < 8) {
    int rrow = M0 + wr + ((l16 >> 2) & 1) * 16 + kq * 4 + (l16 & 3);
    atomicAdd(&f12[rrow], v1[0]);
    atomicAdd(&f12[MTOT + rrow], v2[0]);
  }
  __syncthreads();
  int bb = M0 >> 10, i0 = M0 & 1023;
#pragma unroll
  for (int i = 0; i < 2; ++i) {
    int c = t + i * 512;          // 1024 chunks of 8 shorts
    int row = c >> 3;             // N-row in tile
    int mc = (c & 7) * 8;
    short8 vv = *(const short8*)&T[row * 72 + mc];
    *(short8*)&Wht[((size_t)bb * OUTF + N0 + row) * NNODE + i0 + mc] = vv;
  }
}

// ---------------- masked leaky-relu softmax (f32 out + bf16 copy) ----------------
__global__ __launch_bounds__(256) void softmax_kernel(
    const float* __restrict__ f1, const float* __restrict__ f2,
    const int* __restrict__ adj, float* __restrict__ att,
    short* __restrict__ attbf) {
  int m = blockIdx.x;
  int b = m >> 10;
  int t = threadIdx.x;
  int wave = t >> 6, lane = t & 63;
  __shared__ float red[4];
  float f1v = f1[m];
  int4 av = ((const int4*)(adj + (size_t)m * NNODE))[t];
  float4 fv = ((const float4*)(f2 + b * NNODE))[t];
  float e[4];
  {
    float x;
    x = f1v + fv.x; x = x >= 0.f ? x : 0.2f * x; e[0] = av.x > 0 ? x : -9e15f;
    x = f1v + fv.y; x = x >= 0.f ? x : 0.2f * x; e[1] = av.y > 0 ? x : -9e15f;
    x = f1v + fv.z; x = x >= 0.f ? x : 0.2f * x; e[2] = av.z > 0 ? x : -9e15f;
    x = f1v + fv.w; x = x >= 0.f ? x : 0.2f * x; e[3] = av.w > 0 ? x : -9e15f;
  }
  float mx = fmaxf(fmaxf(e[0], e[1]), fmaxf(e[2], e[3]));
#pragma unroll
  for (int off = 32; off; off >>= 1) mx = fmaxf(mx, __shfl_xor(mx, off));
  if (lane == 0) red[wave] = mx;
  __syncthreads();
  mx = fmaxf(fmaxf(red[0], red[1]), fmaxf(red[2], red[3]));
  __syncthreads();
  float p[4], s = 0.f;
#pragma unroll
  for (int q = 0; q < 4; ++q) { p[q] = expf(e[q] - mx); s += p[q]; }
#pragma unroll
  for (int off = 32; off; off >>= 1) s += __shfl_xor(s, off);
  if (lane == 0) red[wave] = s;
  __syncthreads();
  s = red[0] + red[1] + red[2] + red[3];
  float inv = 1.f / s;
  float4 o = make_float4(p[0] * inv, p[1] * inv, p[2] * inv, p[3] * inv);
  ((float4*)(att + (size_t)m * NNODE))[t] = o;
  short4v ob;
  ob[0] = (short)f2bf(o.x); ob[1] = (short)f2bf(o.y);
  ob[2] = (short)f2bf(o.z); ob[3] = (short)f2bf(o.w);
  ((short4v*)(attbf + (size_t)m * NNODE))[t] = ob;
}

// ---- PV: h_prime = att @ Wh (per batch) ----
// BM=64 BN=128 BK=64, grid 512 (2 blocks/CU), 8 waves, wave 32x32.
__global__ __launch_bounds__(512) void pv_kernel(
    const short* __restrict__ attbf, const short* __restrict__ Wht,
    float* __restrict__ hp) {
  __shared__ short smem[24576];   // 48KB
  int bid0 = blockIdx.x;
  int bid = (bid0 & 7) * 64 + (bid0 >> 3);   // XCD swizzle: one batch per XCD
  int nt = bid & 3, mt = bid >> 2;
  int M0 = mt * 64, N0 = nt * 128;
  const short* Wb = Wht + (size_t)(M0 >> 10) * OUTF * NNODE;
  int t = threadIdx.x;
  int wv = t >> 6, lane = t & 63;
  int wr = (wv >> 2) * 32, wc = (wv & 3) * 32;
  int l16 = lane & 15, kq = lane >> 4;

  floatx4 acc[2][2] = {};

  auto stage = [&](int buf, int kt) {
    {
      int row = t >> 3;
      int cg = (t & 7) ^ (row & 7);
      gload_lds16(&attbf[(size_t)(M0 + row) * NNODE + kt * 64 + cg * 8],
                  &smem[buf * 4096 + (t >> 6) * 512 + (t & 63) * 8]);
    }
#pragma unroll
    for (int i = 0; i < 2; ++i) {
      int q = wv * 64 + lane + i * 512;
      int row = q >> 3;
      int cg = (q & 7) ^ (row & 7);
      gload_lds16(&Wb[(size_t)(N0 + row) * NNODE + kt * 64 + cg * 8],
                  &smem[8192 + buf * 8192 + (wv * 64 + i * 512) * 8]);
    }
  };

  stage(0, 0);
  __syncthreads();
  for (int kt = 0; kt < 16; ++kt) {
    if (kt < 15) stage((kt + 1) & 1, kt + 1);
    const short* As = &smem[(kt & 1) * 4096];
    const short* Bs = &smem[8192 + (kt & 1) * 8192];
#pragma unroll
    for (int ks = 0; ks < 2; ++ks) {
      short8 af[2], bfv[2];
#pragma unroll
      for (int mi = 0; mi < 2; ++mi) {
        int r = wr + mi * 16 + l16;
        af[mi] = *(const short8*)&As[r * 64 + (((ks * 4 + kq) ^ (r & 7)) * 8)];
      }
#pragma unroll
      for (int ni = 0; ni < 2; ++ni) {
        int r = wc + ni * 16 + l16;
        bfv[ni] = *(const short8*)&Bs[r * 64 + (((ks * 4 + kq) ^ (r & 7)) * 8)];
      }
#pragma unroll
      for (int mi = 0; mi < 2; ++mi)
#pragma unroll
        for (int ni = 0; ni < 2; ++ni)
          acc[mi][ni] = __builtin_amdgcn_mfma_f32_16x16x32_bf16(af[mi], bfv[ni], acc[mi][ni], 0, 0, 0);
    }
    __syncthreads();
  }

#pragma unroll
  for (int mi = 0; mi < 2; ++mi)
#pragma unroll
    for (int j = 0; j < 4; ++j) {
      int row = M0 + wr + mi * 16 + kq * 4 + j;
#pragma unroll
      for (int ni = 0; ni < 2; ++ni) {
        int col = N0 + wc + ni * 16 + l16;
        hp[(size_t)row * OUTF + col] = acc[mi][ni][j];
      }
    }
}

extern "C" void kernel_launch(void* const* d_in, const int* in_sizes, int n_in,
                              void* d_out, int out_size, void* d_ws, size_t ws_size,
                              hipStream_t stream) {
  const float* h = (const float*)d_in[0];
  const int* adj = (const int*)d_in[1];
  const int* positions = (const int*)d_in[2];
  const float* W = (const float*)d_in[3];
  const float* a = (const float*)d_in[4];
  const float* pos_table = (const float*)d_in[5];

  float* hp = (float*)d_out;                       // 8192*512
  float* att = hp + (size_t)MTOT * OUTF;           // 8192*1024

  char* ws = (char*)d_ws;
  short* Wt = (short*)ws;                                   // 786432 B
  short* Wht = (short*)(ws + 786432);                       // 8388608 B
  float* f12 = (float*)(ws + 786432 + 8388608);             // 65536 B
  // union region (16777216 B): hbf (dead after gemm1) / attbf
  short* hbf = (short*)(ws + 786432 + 8388608 + 65536);
  short* attbf = hbf;

  prep_kernel<<<3456, 256, 0, stream>>>(h, W, hbf, Wt, f12);
  gemm1_kernel<<<512, 512, 0, stream>>>(hbf, Wt, positions, pos_table, a, f12, Wht);
  softmax_kernel<<<8192, 256, 0, stream>>>(f12, f12 + MTOT, adj, att, attbf);
  pv_kernel<<<512, 512, 0, stream>>>(attbf, Wht, hp);
}